// Round 2
// baseline (309.128 us; speedup 1.0000x reference)
//
#include <hip/hip_runtime.h>
#include <hip/hip_bf16.h>
#include <math.h>

#define IN_CH 128
#define OUT_CH 16
#define K_HOPS 2

// ---------------- degree / norm ----------------

__global__ void k_init_deg(float* deg, int N) {
    int i = blockIdx.x * blockDim.x + threadIdx.x;
    if (i < N) deg[i] = 1.0f;  // self-loop weight
}

__global__ void k_deg_accum(const int* __restrict__ col, const float* __restrict__ ew,
                            float* deg, int E) {
    int e = blockIdx.x * blockDim.x + threadIdx.x;
    if (e < E) atomicAdd(&deg[col[e]], ew[e]);
}

__global__ void k_dinv(const float* __restrict__ deg, float* dinv, float* selfnorm, int N) {
    int i = blockIdx.x * blockDim.x + threadIdx.x;
    if (i < N) {
        float d = rsqrtf(deg[i]);   // deg >= 1 always (self loop)
        dinv[i] = d;
        selfnorm[i] = d * d;
    }
}

__global__ void k_norm(const int* __restrict__ row, const int* __restrict__ col,
                       const float* __restrict__ ew, const float* __restrict__ dinv,
                       float* nrm, int E) {
    int e = blockIdx.x * blockDim.x + threadIdx.x;
    if (e < E) nrm[e] = dinv[row[e]] * ew[e] * dinv[col[e]];
}

// ---------------- projection: y = x @ W^T ----------------
// block = 256 threads -> 16 rows/block, thread (t>>4)=local row, (t&15)=out ch

__global__ void k_proj(const float* __restrict__ x, const float* __restrict__ W,
                       float* __restrict__ y, int N) {
    __shared__ float sW[OUT_CH * (IN_CH + 1)];  // +1 pad: stride 129 kills bank conflict
    for (int i = threadIdx.x; i < OUT_CH * IN_CH; i += blockDim.x) {
        int o = i >> 7, k = i & 127;
        sW[o * (IN_CH + 1) + k] = W[i];
    }
    __syncthreads();
    int t = threadIdx.x;
    int n = blockIdx.x * 16 + (t >> 4);
    int o = t & 15;
    if (n >= N) return;
    const float* xr = x + (size_t)n * IN_CH;
    const float* wr = sW + o * (IN_CH + 1);
    float acc = 0.0f;
#pragma unroll
    for (int k = 0; k < IN_CH; k += 4) {
        float4 xv = *reinterpret_cast<const float4*>(xr + k);
        acc += xv.x * wr[k] + xv.y * wr[k + 1] + xv.z * wr[k + 2] + xv.w * wr[k + 3];
    }
    y[(size_t)n * OUT_CH + o] = acc;
}

// ---------------- propagation hop ----------------

// h_out[i][c] = selfnorm[i] * h_in[i][c]   (also serves as the zero-init)
__global__ void k_selfinit(const float* __restrict__ hin, const float* __restrict__ selfnorm,
                           float* __restrict__ hout, int N) {
    int idx = blockIdx.x * blockDim.x + threadIdx.x;
    if (idx < N * OUT_CH) {
        int n = idx >> 4;
        hout[idx] = selfnorm[n] * hin[idx];
    }
}

// 16 threads per edge: h_out[col][c] += norm[e] * h_in[row][c]
__global__ void k_scatter(const int* __restrict__ row, const int* __restrict__ col,
                          const float* __restrict__ nrm, const float* __restrict__ hin,
                          float* __restrict__ hout, int E) {
    long long idx = (long long)blockIdx.x * blockDim.x + threadIdx.x;
    int e = (int)(idx >> 4);
    int c = (int)(idx & 15);
    if (e >= E) return;
    int r  = row[e];
    int cl = col[e];
    atomicAdd(&hout[(size_t)cl * OUT_CH + c], nrm[e] * hin[(size_t)r * OUT_CH + c]);
}

// ---------------- log_softmax over 16 classes ----------------

__global__ void k_lsm(const float* __restrict__ h, float* __restrict__ out, int N) {
    int n = blockIdx.x * blockDim.x + threadIdx.x;
    if (n >= N) return;
    const float* hr = h + (size_t)n * OUT_CH;
    float v[OUT_CH];
    float4 a = reinterpret_cast<const float4*>(hr)[0];
    float4 b = reinterpret_cast<const float4*>(hr)[1];
    float4 c = reinterpret_cast<const float4*>(hr)[2];
    float4 d = reinterpret_cast<const float4*>(hr)[3];
    v[0]=a.x; v[1]=a.y; v[2]=a.z; v[3]=a.w;
    v[4]=b.x; v[5]=b.y; v[6]=b.z; v[7]=b.w;
    v[8]=c.x; v[9]=c.y; v[10]=c.z; v[11]=c.w;
    v[12]=d.x; v[13]=d.y; v[14]=d.z; v[15]=d.w;
    float m = v[0];
#pragma unroll
    for (int i = 1; i < OUT_CH; i++) m = fmaxf(m, v[i]);
    float s = 0.0f;
#pragma unroll
    for (int i = 0; i < OUT_CH; i++) s += expf(v[i] - m);
    float lse = m + logf(s);
    float* orow = out + (size_t)n * OUT_CH;
#pragma unroll
    for (int i = 0; i < OUT_CH; i++) orow[i] = v[i] - lse;
}

// ---------------- launch ----------------

extern "C" void kernel_launch(void* const* d_in, const int* in_sizes, int n_in,
                              void* d_out, int out_size, void* d_ws, size_t ws_size,
                              hipStream_t stream) {
    const float* x  = (const float*)d_in[0];
    const float* W  = (const float*)d_in[1];
    const float* ew = (const float*)d_in[2];
    const int*   ei = (const int*)d_in[3];   // harness converts int64 -> int32
    // d_in[4] = K (1-element int array); fixed at 2 per the reference.

    int N = in_sizes[0] / IN_CH;
    int E = in_sizes[2];
    const int* row = ei;       // source
    const int* col = ei + E;   // target

    auto align256 = [](size_t v) { return (v + 255) & ~(size_t)255; };
    size_t szN   = align256((size_t)N * 4);
    size_t szE   = align256((size_t)E * 4);
    size_t szN16 = align256((size_t)N * OUT_CH * 4);

    char* ws = (char*)d_ws;
    float* deg      = (float*)(ws);
    float* dinv     = (float*)(ws + szN);
    float* selfnorm = (float*)(ws + 2 * szN);
    float* nrm      = (float*)(ws + 3 * szN);
    float* h0       = (float*)(ws + 3 * szN + szE);
    float* h1       = (float*)(ws + 3 * szN + szE + szN16);

    const int B = 256;
    int gN   = (N + B - 1) / B;
    int gE   = (E + B - 1) / B;
    int gN16 = (N * OUT_CH + B - 1) / B;
    long long scat = (long long)E * OUT_CH;
    int gScat = (int)((scat + B - 1) / B);

    // 1) degrees + norms
    k_init_deg<<<gN, B, 0, stream>>>(deg, N);
    k_deg_accum<<<gE, B, 0, stream>>>(col, ew, deg, E);
    k_dinv<<<gN, B, 0, stream>>>(deg, dinv, selfnorm, N);
    k_norm<<<gE, B, 0, stream>>>(row, col, ew, dinv, nrm, E);

    // 2) projection first (commutes with propagation): h0 = x @ W^T
    k_proj<<<(N + 15) / 16, B, 0, stream>>>(x, W, h0, N);

    // 3) K=2 hops, ping-pong h0 <-> h1
    float* hin = h0;
    float* hout = h1;
    for (int k = 0; k < K_HOPS; k++) {
        k_selfinit<<<gN16, B, 0, stream>>>(hin, selfnorm, hout, N);
        k_scatter<<<gScat, B, 0, stream>>>(row, col, nrm, hin, hout, E);
        float* tmp = hin; hin = hout; hout = tmp;
    }

    // 4) log_softmax -> d_out
    k_lsm<<<gN, B, 0, stream>>>(hin, (float*)d_out, N);
}

// Round 3
// 301.152 us; speedup vs baseline: 1.0265x; 1.0265x over previous
//
#include <hip/hip_runtime.h>
#include <hip/hip_bf16.h>
#include <math.h>

#define IN_CH 128
#define OUT_CH 16
#define K_HOPS 2
#define NXCD 8

// ---------------- helpers ----------------

__device__ __forceinline__ int xcc_id() {
    int x;
    asm volatile("s_getreg_b32 %0, hwreg(HW_REG_XCC_ID, 0, 32)" : "=s"(x));
    return x & (NXCD - 1);
}

__device__ __forceinline__ void atom_add(float* p, float v, bool local) {
    if (local)
        __hip_atomic_fetch_add(p, v, __ATOMIC_RELAXED, __HIP_MEMORY_SCOPE_WORKGROUP);
    else
        atomicAdd(p, v);
}

// ---------------- zero scratch (float4 grid-stride) ----------------

__global__ void k_zero4(float4* p, long long n4) {
    long long stride = (long long)gridDim.x * blockDim.x;
    for (long long i = (long long)blockIdx.x * blockDim.x + threadIdx.x; i < n4; i += stride)
        p[i] = make_float4(0.f, 0.f, 0.f, 0.f);
}

// ---------------- degree accumulation (privatized per XCD) ----------------

template <bool LOCAL>
__global__ void k_deg(const int* __restrict__ col, const float* __restrict__ ew,
                      float* __restrict__ degc, int N, int E) {
    int xcd = LOCAL ? xcc_id() : 0;
    float* dst = degc + (size_t)xcd * N;
    int stride = gridDim.x * blockDim.x;
    for (int e = blockIdx.x * blockDim.x + threadIdx.x; e < E; e += stride)
        atom_add(&dst[col[e]], ew[e], LOCAL);
}

// dinv[i] = rsqrt(1 + sum_x degc[x][i]);  selfnorm = dinv^2
__global__ void k_dinv(const float* __restrict__ degc, float* __restrict__ dinv,
                       float* __restrict__ selfnorm, int N, int NC) {
    int i = blockIdx.x * blockDim.x + threadIdx.x;
    if (i >= N) return;
    float d = 1.0f;  // self-loop
    for (int x = 0; x < NC; ++x) d += degc[(size_t)x * N + i];
    float r = rsqrtf(d);
    dinv[i] = r;
    selfnorm[i] = r * r;
}

// ---------------- projection: h0 = x @ W^T ----------------

__global__ void k_proj(const float* __restrict__ x, const float* __restrict__ W,
                       float* __restrict__ y, int N) {
    __shared__ float sW[OUT_CH * (IN_CH + 1)];
    for (int i = threadIdx.x; i < OUT_CH * IN_CH; i += blockDim.x) {
        int o = i >> 7, k = i & 127;
        sW[o * (IN_CH + 1) + k] = W[i];
    }
    __syncthreads();
    int t = threadIdx.x;
    int n = blockIdx.x * 16 + (t >> 4);
    int o = t & 15;
    if (n >= N) return;
    const float* xr = x + (size_t)n * IN_CH;
    const float* wr = sW + o * (IN_CH + 1);
    float acc = 0.0f;
#pragma unroll
    for (int k = 0; k < IN_CH; k += 4) {
        float4 xv = *reinterpret_cast<const float4*>(xr + k);
        acc += xv.x * wr[k] + xv.y * wr[k + 1] + xv.z * wr[k + 2] + xv.w * wr[k + 3];
    }
    y[(size_t)n * OUT_CH + o] = acc;
}

// ---------------- hop 1 scatter (fused norm computation) ----------------
// 16 lanes per edge: hc[xcd][col][c] += (dinv[r]*ew*dinv[cl]) * h[r][c]; also writes nrm[e]

template <bool LOCAL>
__global__ void k_scat1(const int* __restrict__ row, const int* __restrict__ col,
                        const float* __restrict__ ew, const float* __restrict__ dinv,
                        const float* __restrict__ h, float* __restrict__ nrm,
                        float* __restrict__ hc, int N, int E) {
    int xcd = LOCAL ? xcc_id() : 0;
    float* dst = hc + (size_t)xcd * N * OUT_CH;
    long long stride = (long long)gridDim.x * blockDim.x;
    long long tot = (long long)E * OUT_CH;
    for (long long i = (long long)blockIdx.x * blockDim.x + threadIdx.x; i < tot; i += stride) {
        int e = (int)(i >> 4);
        int c = (int)(i & 15);
        int r = row[e], cl = col[e];
        float nv = dinv[r] * ew[e] * dinv[cl];
        if (c == 0) nrm[e] = nv;
        float v = nv * h[(size_t)r * OUT_CH + c];
        atom_add(&dst[(size_t)cl * OUT_CH + c], v, LOCAL);
    }
}

// ---------------- hop 2 scatter (uses precomputed nrm) ----------------

template <bool LOCAL>
__global__ void k_scat2(const int* __restrict__ row, const int* __restrict__ col,
                        const float* __restrict__ nrm, const float* __restrict__ h,
                        float* __restrict__ hc, int N, int E) {
    int xcd = LOCAL ? xcc_id() : 0;
    float* dst = hc + (size_t)xcd * N * OUT_CH;
    long long stride = (long long)gridDim.x * blockDim.x;
    long long tot = (long long)E * OUT_CH;
    for (long long i = (long long)blockIdx.x * blockDim.x + threadIdx.x; i < tot; i += stride) {
        int e = (int)(i >> 4);
        int c = (int)(i & 15);
        int r = row[e], cl = col[e];
        float v = nrm[e] * h[(size_t)r * OUT_CH + c];
        atom_add(&dst[(size_t)cl * OUT_CH + c], v, LOCAL);
    }
}

// ---------------- hop 1 reduce: h1 = selfnorm*h0 + sum_x hc[x]; re-zero hc ----------------

__global__ void k_red1(const float* __restrict__ hin, const float* __restrict__ selfnorm,
                       float* __restrict__ hc, float* __restrict__ hout, int N, int NC) {
    int i4 = blockIdx.x * blockDim.x + threadIdx.x;  // float4 index over N*16 floats
    int n4 = N * (OUT_CH / 4);
    if (i4 >= n4) return;
    size_t N16 = (size_t)N * OUT_CH;
    float4 acc = reinterpret_cast<const float4*>(hin)[i4];
    float s = selfnorm[i4 >> 2];
    acc.x *= s; acc.y *= s; acc.z *= s; acc.w *= s;
    for (int x = 0; x < NC; ++x) {
        float4* p = reinterpret_cast<float4*>(hc + (size_t)x * N16) + i4;
        float4 v = *p;
        acc.x += v.x; acc.y += v.y; acc.z += v.z; acc.w += v.w;
        *p = make_float4(0.f, 0.f, 0.f, 0.f);  // re-zero for hop 2
    }
    reinterpret_cast<float4*>(hout)[i4] = acc;
}

// ---------------- hop 2 reduce fused with log_softmax ----------------

__global__ void k_red2_lsm(const float* __restrict__ hin, const float* __restrict__ selfnorm,
                           const float* __restrict__ hc, float* __restrict__ out, int N, int NC) {
    int n = blockIdx.x * blockDim.x + threadIdx.x;
    if (n >= N) return;
    size_t base = (size_t)n * OUT_CH;
    size_t N16 = (size_t)N * OUT_CH;
    float s = selfnorm[n];
    float v[OUT_CH];
    float4* vv = reinterpret_cast<float4*>(v);
#pragma unroll
    for (int q = 0; q < 4; ++q) {
        float4 a = reinterpret_cast<const float4*>(hin + base)[q];
        a.x *= s; a.y *= s; a.z *= s; a.w *= s;
        vv[q] = a;
    }
    for (int x = 0; x < NC; ++x) {
        const float4* p = reinterpret_cast<const float4*>(hc + (size_t)x * N16 + base);
#pragma unroll
        for (int q = 0; q < 4; ++q) {
            float4 a = p[q];
            vv[q].x += a.x; vv[q].y += a.y; vv[q].z += a.z; vv[q].w += a.w;
        }
    }
    float m = v[0];
#pragma unroll
    for (int i = 1; i < OUT_CH; i++) m = fmaxf(m, v[i]);
    float sum = 0.0f;
#pragma unroll
    for (int i = 0; i < OUT_CH; i++) sum += expf(v[i] - m);
    float lse = m + logf(sum);
    float* orow = out + base;
#pragma unroll
    for (int i = 0; i < OUT_CH; i++) orow[i] = v[i] - lse;
}

// ---------------- launch ----------------

extern "C" void kernel_launch(void* const* d_in, const int* in_sizes, int n_in,
                              void* d_out, int out_size, void* d_ws, size_t ws_size,
                              hipStream_t stream) {
    const float* x  = (const float*)d_in[0];
    const float* W  = (const float*)d_in[1];
    const float* ew = (const float*)d_in[2];
    const int*   ei = (const int*)d_in[3];  // harness pushes int64 as int32

    int N = in_sizes[0] / IN_CH;
    int E = in_sizes[2];
    const int* row = ei;       // source
    const int* col = ei + E;   // target

    auto al = [](size_t v) { return (v + 255) & ~(size_t)255; };
    size_t N16 = (size_t)N * OUT_CH;

    // try NC=8 (per-XCD privatized); fall back to NC=1 device-scope if ws too small
    int NC = NXCD;
    size_t need;
    size_t o_dinv, o_self, o_nrm, o_h0, o_h1, o_degc, o_hc;
    for (;;) {
        o_dinv = 0;
        o_self = o_dinv + al((size_t)N * 4);
        o_nrm  = o_self + al((size_t)N * 4);
        o_h0   = o_nrm  + al((size_t)E * 4);
        o_h1   = o_h0   + al(N16 * 4);
        o_degc = o_h1   + al(N16 * 4);
        o_hc   = o_degc + al((size_t)NC * N * 4);
        need   = o_hc   + al((size_t)NC * N16 * 4);
        if (need <= ws_size || NC == 1) break;
        NC = 1;
    }
    bool local = (NC == NXCD);

    char* ws = (char*)d_ws;
    float* dinv     = (float*)(ws + o_dinv);
    float* selfnorm = (float*)(ws + o_self);
    float* nrm      = (float*)(ws + o_nrm);
    float* h0       = (float*)(ws + o_h0);
    float* h1       = (float*)(ws + o_h1);
    float* degc     = (float*)(ws + o_degc);
    float* hc       = (float*)(ws + o_hc);

    const int B = 256;

    // 1) zero degc..hc (contiguous region, incl. alignment gaps)
    long long zb = (long long)(need - o_degc);
    long long z4 = zb / 16;
    int gz = (int)((z4 + B - 1) / B);
    if (gz > 4096) gz = 4096;
    k_zero4<<<gz, B, 0, stream>>>((float4*)(ws + o_degc), z4);

    // 2) degree accumulation (local-L2 atomics when privatized)
    if (local) k_deg<true ><<<2048, B, 0, stream>>>(col, ew, degc, N, E);
    else       k_deg<false><<<2048, B, 0, stream>>>(col, ew, degc, N, E);

    // 3) dinv + selfnorm
    k_dinv<<<(N + B - 1) / B, B, 0, stream>>>(degc, dinv, selfnorm, N, NC);

    // 4) projection (commutes with propagation): h0 = x @ W^T
    k_proj<<<(N + 15) / 16, B, 0, stream>>>(x, W, h0, N);

    // 5) hop 1: scatter (fused norm) + reduce (fused self-loop, re-zeros hc)
    if (local) k_scat1<true ><<<8192, B, 0, stream>>>(row, col, ew, dinv, h0, nrm, hc, N, E);
    else       k_scat1<false><<<8192, B, 0, stream>>>(row, col, ew, dinv, h0, nrm, hc, N, E);
    int g4 = (int)((N16 / 4 + B - 1) / B);
    k_red1<<<g4, B, 0, stream>>>(h0, selfnorm, hc, h1, N, NC);

    // 6) hop 2: scatter (precomputed nrm) + reduce fused with log_softmax -> d_out
    if (local) k_scat2<true ><<<8192, B, 0, stream>>>(row, col, nrm, h1, hc, N, E);
    else       k_scat2<false><<<8192, B, 0, stream>>>(row, col, nrm, h1, hc, N, E);
    k_red2_lsm<<<(N + B - 1) / B, B, 0, stream>>>(h1, selfnorm, hc, (float*)d_out, N, NC);
}